// Round 1
// baseline (668.290 us; speedup 1.0000x reference)
//
#include <hip/hip_runtime.h>
#include <hip/hip_bf16.h>

// Problem constants
constexpr int B = 4;
constexpr int N = 1024;
constexpr int D = 1024;
constexpr int H = 16;
constexpr int DEPTH = 64;   // D / H
constexpr int W = 32;

// ---------------------------------------------------------------------------
// fp32 tiled GEMM: C[M,Nn] = A[M,K] @ Wt[K,Nn] + bias[Nn]
// 64x64 tile, BK=16, 256 threads, 4x4 microtile per thread.
// ---------------------------------------------------------------------------
constexpr int TS = 64;
constexpr int BK = 16;

__global__ __launch_bounds__(256) void gemm_bias(
    const float* __restrict__ A, const float* __restrict__ Wt,
    const float* __restrict__ bias, float* __restrict__ C,
    int M, int K, int Nn) {
  __shared__ float As[BK][TS];   // As[k][m]
  __shared__ float Bs[BK][TS];   // Bs[k][n]

  const int tid = threadIdx.x;
  const int bm = blockIdx.y * TS;
  const int bn = blockIdx.x * TS;
  const int tx = tid & 15;       // 0..15 -> 4 output cols
  const int ty = tid >> 4;       // 0..15 -> 4 output rows

  // A load: each thread one float4: row am (0..63), k-cols ak..ak+3
  const int am = tid >> 2;
  const int ak = (tid & 3) << 2;
  // B load: each thread one float4: k-row bk_, cols bn4..bn4+3
  const int bk_ = tid >> 4;
  const int bn4 = (tid & 15) << 2;

  float acc[4][4] = {};

  for (int k0 = 0; k0 < K; k0 += BK) {
    float4 av = *(const float4*)(A + (size_t)(bm + am) * K + k0 + ak);
    float4 bv = *(const float4*)(Wt + (size_t)(k0 + bk_) * Nn + bn + bn4);
    As[ak + 0][am] = av.x;
    As[ak + 1][am] = av.y;
    As[ak + 2][am] = av.z;
    As[ak + 3][am] = av.w;
    *(float4*)&Bs[bk_][bn4] = bv;
    __syncthreads();

#pragma unroll
    for (int kk = 0; kk < BK; kk++) {
      float4 a4 = *(const float4*)&As[kk][ty << 2];
      float4 b4 = *(const float4*)&Bs[kk][tx << 2];
      float a[4] = {a4.x, a4.y, a4.z, a4.w};
      float b[4] = {b4.x, b4.y, b4.z, b4.w};
#pragma unroll
      for (int i = 0; i < 4; i++)
#pragma unroll
        for (int j = 0; j < 4; j++) acc[i][j] += a[i] * b[j];
    }
    __syncthreads();
  }

#pragma unroll
  for (int i = 0; i < 4; i++) {
    const int row = bm + (ty << 2) + i;
#pragma unroll
    for (int j = 0; j < 4; j++) {
      const int col = bn + (tx << 2) + j;
      C[(size_t)row * Nn + col] = acc[i][j] + bias[col];
    }
  }
}

// ---------------------------------------------------------------------------
// Vsum[b, d] = sum over n of v[b, n, d]
// ---------------------------------------------------------------------------
__global__ __launch_bounds__(256) void vsum_kernel(const float* __restrict__ v,
                                                   float* __restrict__ vsum) {
  const int idx = blockIdx.x * 256 + threadIdx.x;  // b*D + d
  const int b = idx >> 10;
  const int d = idx & (D - 1);
  const float* p = v + (size_t)b * N * D + d;
  float s = 0.f;
  for (int n = 0; n < N; n++) s += p[(size_t)n * D];
  vsum[idx] = s;
}

// ---------------------------------------------------------------------------
// pass1: per (b,h,n): gather-dot 32 keys, closed-form full-row softmax,
// p_w + base out to ws; out[b,n,h*64+d] = base*Vsum + sum_w (p_w-base)*v[g_w]
// One wave (64 threads) per row.
// ---------------------------------------------------------------------------
__global__ __launch_bounds__(64) void attn_pass1(
    const float* __restrict__ q, const float* __restrict__ k,
    const float* __restrict__ v, const float* __restrict__ vsum,
    const int* __restrict__ graph, float* __restrict__ pbuf,
    float* __restrict__ basebuf, float* __restrict__ outbuf) {
  const int bid = blockIdx.x;          // (b*H + h)*N + n
  const int n = bid & (N - 1);
  const int h = (bid >> 10) & (H - 1);
  const int b = bid >> 14;
  const int lane = threadIdx.x;

  __shared__ float q_sh[DEPTH];
  __shared__ int g_sh[W];
  __shared__ float p_sh[W];

  const float* qrow = q + ((size_t)b * N + n) * D + h * DEPTH;
  q_sh[lane] = qrow[lane];
  if (lane < W) g_sh[lane] = graph[n * W + lane];
  __syncthreads();

  // lane pair (2w, 2w+1) computes dot for graph slot w (32 dims each half)
  const int w = lane >> 1;
  const int half = lane & 1;
  const float* krow = k + ((size_t)b * N + g_sh[w]) * D + h * DEPTH + half * 32;
  float acc = 0.f;
#pragma unroll
  for (int j4 = 0; j4 < 8; j4++) {
    float4 kv = *(const float4*)(krow + j4 * 4);
    const float* qh = &q_sh[half * 32 + j4 * 4];
    acc += kv.x * qh[0] + kv.y * qh[1] + kv.z * qh[2] + kv.w * qh[3];
  }
  acc += __shfl_xor(acc, 1);
  const float dot = acc * 0.125f;  // / sqrt(64)

  // row max over {dots} U {0}
  float m = dot;
#pragma unroll
  for (int off = 2; off < 64; off <<= 1) m = fmaxf(m, __shfl_xor(m, off));
  m = fmaxf(m, 0.f);

  const float e = expf(dot - m);
  float s = e;
#pragma unroll
  for (int off = 1; off < 64; off <<= 1) s += __shfl_xor(s, off);
  s *= 0.5f;  // each w counted twice (lane pairs)

  const float em = expf(-m);
  const float Z = (float)(N - W) * em + s;
  const float inv = 1.f / Z;
  const float base = em * inv;
  const float pw = e * inv;

  if (half == 0) p_sh[w] = pw;
  __syncthreads();

  if (half == 0) pbuf[(size_t)bid * W + w] = pw;
  if (lane == 0) basebuf[bid] = base;

  // out[b,h,n,:] = base * Vsum[b,h,:] + sum_w (p_w - base) * v[b, g_w, h,:]
  float ov = base * vsum[b * D + h * DEPTH + lane];
#pragma unroll 4
  for (int ww = 0; ww < W; ww++) {
    ov += (p_sh[ww] - base) * v[((size_t)b * N + g_sh[ww]) * D + h * DEPTH + lane];
  }
  outbuf[((size_t)b * N + n) * D + h * DEPTH + lane] = ov;
}

// ---------------------------------------------------------------------------
// pass2: fill attn row: base everywhere, p_w at graph positions.
// One 256-thread block per row; 4KB LDS row staging; float4 store.
// ---------------------------------------------------------------------------
__global__ __launch_bounds__(256) void attn_fill(
    const float* __restrict__ pbuf, const float* __restrict__ basebuf,
    const int* __restrict__ graph, float* __restrict__ attn) {
  const int bid = blockIdx.x;  // (b*H + h)*N + n
  const int n = bid & (N - 1);
  __shared__ float row[N];

  const float base = basebuf[bid];
  float4 b4 = {base, base, base, base};
  float4* row4 = (float4*)row;
  row4[threadIdx.x] = b4;
  __syncthreads();
  if (threadIdx.x < W) {
    const int g = graph[n * W + threadIdx.x];
    row[g] = pbuf[(size_t)bid * W + threadIdx.x];
  }
  __syncthreads();
  float4* dst = (float4*)(attn + (size_t)bid * N);
  dst[threadIdx.x] = row4[threadIdx.x];
}

// ---------------------------------------------------------------------------
extern "C" void kernel_launch(void* const* d_in, const int* in_sizes, int n_in,
                              void* d_out, int out_size, void* d_ws, size_t ws_size,
                              hipStream_t stream) {
  const float* hidden = (const float*)d_in[0];
  const float* wq = (const float*)d_in[1];
  const float* bq = (const float*)d_in[2];
  const float* wk = (const float*)d_in[3];
  const float* bk = (const float*)d_in[4];
  const float* wv = (const float*)d_in[5];
  const float* bv = (const float*)d_in[6];
  const float* wo = (const float*)d_in[7];
  const float* bo = (const float*)d_in[8];
  const int* graph = (const int*)d_in[9];

  float* out0 = (float*)d_out;                       // (B,N,D) final output
  float* attnp = out0 + (size_t)B * N * D;           // (B,H,N,N) attn

  // Stage q,k,v,out-pre-projection INSIDE the attn region (written last).
  const size_t PLANE = (size_t)B * N * D;            // 4,194,304 floats
  float* qb = attnp;
  float* kb = attnp + PLANE;
  float* vb = attnp + 2 * PLANE;
  float* ob = attnp + 3 * PLANE;

  // Small workspace: p values, base, vsum (~8.7 MB)
  float* pbuf = (float*)d_ws;                        // B*H*N*W = 2,097,152
  float* basebuf = pbuf + (size_t)B * H * N * W;     // 65,536
  float* vsumb = basebuf + (size_t)B * H * N;        // 4,096

  dim3 ggrid(D / TS, (B * N) / TS);  // (16, 64)

  gemm_bias<<<ggrid, 256, 0, stream>>>(hidden, wq, bq, qb, B * N, D, D);
  gemm_bias<<<ggrid, 256, 0, stream>>>(hidden, wk, bk, kb, B * N, D, D);
  gemm_bias<<<ggrid, 256, 0, stream>>>(hidden, wv, bv, vb, B * N, D, D);

  vsum_kernel<<<(B * D) / 256, 256, 0, stream>>>(vb, vsumb);

  attn_pass1<<<B * H * N, 64, 0, stream>>>(qb, kb, vb, vsumb, graph, pbuf,
                                           basebuf, ob);

  // O-projection BEFORE attn fill (ob lives in the attn region).
  gemm_bias<<<ggrid, 256, 0, stream>>>(ob, wo, bo, out0, B * N, D, D);

  attn_fill<<<B * H * N, 256, 0, stream>>>(pbuf, basebuf, graph, attnp);
}

// Round 2
// 349.058 us; speedup vs baseline: 1.9146x; 1.9146x over previous
//
#include <hip/hip_runtime.h>
#include <hip/hip_bf16.h>

constexpr int B = 4;
constexpr int N = 1024;
constexpr int D = 1024;
constexpr int H = 16;
constexpr int DEPTH = 64;
constexpr int W = 32;
constexpr int LDQKV = 3072;   // fused q|k|v row stride

typedef __bf16 bf16x8 __attribute__((ext_vector_type(8)));
typedef float f32x4 __attribute__((ext_vector_type(4)));
typedef unsigned short us8 __attribute__((ext_vector_type(8)));

// ---------------------------------------------------------------------------
// async global->LDS, 16B per lane. LDS dest must be wave-uniform base;
// HW adds lane*16. Low 32 bits of a generic LDS pointer are the LDS offset.
// ---------------------------------------------------------------------------
__device__ __forceinline__ void load_lds16(const void* g, void* l) {
  unsigned int lo = (unsigned int)(unsigned long long)l;
  __builtin_amdgcn_global_load_lds(
      (const __attribute__((address_space(1))) unsigned int*)g,
      (__attribute__((address_space(3))) unsigned int*)lo, 16, 0, 0);
}

// ---------------------------------------------------------------------------
// split fp32 x -> bf16 hi + bf16 lo (hi = rne(x), lo = rne(x - hi))
// elementwise, 8 elems/thread
// ---------------------------------------------------------------------------
__global__ __launch_bounds__(256) void cvt_split(const float* __restrict__ x,
                                                 unsigned short* __restrict__ hi,
                                                 unsigned short* __restrict__ lo) {
  const size_t i = ((size_t)blockIdx.x * 256 + threadIdx.x) * 8;
  float4 a = *(const float4*)(x + i);
  float4 b = *(const float4*)(x + i + 4);
  float xs[8] = {a.x, a.y, a.z, a.w, b.x, b.y, b.z, b.w};
  us8 hv, lv;
#pragma unroll
  for (int j = 0; j < 8; j++) {
    __bf16 h = (__bf16)xs[j];
    float rem = xs[j] - (float)h;
    __bf16 l = (__bf16)rem;
    hv[j] = __builtin_bit_cast(unsigned short, h);
    lv[j] = __builtin_bit_cast(unsigned short, l);
  }
  *(us8*)(hi + i) = hv;
  *(us8*)(lo + i) = lv;
}

// ---------------------------------------------------------------------------
// weight [K=1024][N=1024] -> transposed split BT[rowOff+n][k] (bf16 hi/lo)
// 64x64 tile via LDS
// ---------------------------------------------------------------------------
__global__ __launch_bounds__(256) void txp_cvt(const float* __restrict__ w,
                                               unsigned short* __restrict__ bth,
                                               unsigned short* __restrict__ btl,
                                               int rowOff) {
  __shared__ float sf[64][65];
  const int t = threadIdx.x;
  const int tn = (blockIdx.x & 15) * 64;  // src col block
  const int tk = (blockIdx.x >> 4) * 64;  // src row block
#pragma unroll
  for (int i = 0; i < 4; i++) {
    int f = i * 256 + t;
    int r = f >> 4, c4 = (f & 15) * 4;
    float4 v = *(const float4*)(w + (size_t)(tk + r) * 1024 + tn + c4);
    sf[r][c4 + 0] = v.x; sf[r][c4 + 1] = v.y;
    sf[r][c4 + 2] = v.z; sf[r][c4 + 3] = v.w;
  }
  __syncthreads();
  const int n = t >> 2;            // out row (src col)
  const int kc = (t & 3) * 16;     // k chunk
  us8 hv[2], lv[2];
#pragma unroll
  for (int half = 0; half < 2; half++) {
#pragma unroll
    for (int j = 0; j < 8; j++) {
      float x = sf[kc + half * 8 + j][n];
      __bf16 h = (__bf16)x;
      float rem = x - (float)h;
      __bf16 l = (__bf16)rem;
      hv[half][j] = __builtin_bit_cast(unsigned short, h);
      lv[half][j] = __builtin_bit_cast(unsigned short, l);
    }
  }
  size_t dst = (size_t)(rowOff + tn + n) * 1024 + tk + kc;
  *(us8*)(bth + dst) = hv[0];
  *(us8*)(bth + dst + 8) = hv[1];
  *(us8*)(btl + dst) = lv[0];
  *(us8*)(btl + dst + 8) = lv[1];
}

__global__ void bias_concat(const float* __restrict__ bq, const float* __restrict__ bk,
                            const float* __restrict__ bv, float* __restrict__ dst) {
  int i = blockIdx.x * 256 + threadIdx.x;
  dst[i] = i < 1024 ? bq[i] : (i < 2048 ? bk[i - 1024] : bv[i - 2048]);
}

// ---------------------------------------------------------------------------
// Split-bf16 MFMA GEMM: C[M][Nn] = Ah@Bh + Ah@Bl + Al@Bh + bias
// A planes [M][K] bf16; BT planes [Nn][K] bf16 (pre-transposed). K=1024.
// 128x128 tile, BK=32, 4 waves, 16x16x32 MFMA, 4x4 frags/wave.
// LDS tiles [128][32] with granule swizzle k' = k ^ ((r>>1)&3) applied on the
// global SOURCE address (LDS dest stays linear for global_load_lds) and on
// the ds_read address. 2-way bank aliasing only (free).
// ---------------------------------------------------------------------------
__global__ __launch_bounds__(256) void gemm_split(
    const unsigned short* __restrict__ Ah, const unsigned short* __restrict__ Al,
    const unsigned short* __restrict__ Bth, const unsigned short* __restrict__ Btl,
    const float* __restrict__ bias, float* __restrict__ C,
    int K, int Nn) {
  __shared__ __align__(16) unsigned short sAh[128 * 32];
  __shared__ __align__(16) unsigned short sAl[128 * 32];
  __shared__ __align__(16) unsigned short sBh[128 * 32];
  __shared__ __align__(16) unsigned short sBl[128 * 32];

  const int tid = threadIdx.x;
  const int lane = tid & 63;
  const int wave = tid >> 6;
  const int wr = wave >> 1, wc = wave & 1;
  const int bm = blockIdx.y * 128, bn = blockIdx.x * 128;

  // staging: 8KB/tile = 8 chunks of 64 lanes x 16B; wave handles chunks w, w+4
  size_t aoff[2], boff[2];
  int ldsoff[2];
#pragma unroll
  for (int c = 0; c < 2; c++) {
    const int chunk = wave + 4 * c;
    const int e = chunk * 512 + lane * 8;   // linear LDS element
    const int r = e >> 5;                   // tile row
    const int kpos = (e >> 3) & 3;          // granule position in row
    const int ksrc = kpos ^ ((r >> 1) & 3); // swizzle: source granule
    aoff[c] = (size_t)(bm + r) * K + ksrc * 8;
    boff[c] = (size_t)(bn + r) * K + ksrc * 8;
    ldsoff[c] = chunk * 512;
  }

  const int fr = lane & 15;
  const int fkg = lane >> 4;

  f32x4 acc[4][4] = {};

  for (int k0 = 0; k0 < K; k0 += 32) {
#pragma unroll
    for (int c = 0; c < 2; c++) {
      load_lds16(Ah + aoff[c] + k0, sAh + ldsoff[c]);
      load_lds16(Al + aoff[c] + k0, sAl + ldsoff[c]);
      load_lds16(Bth + boff[c] + k0, sBh + ldsoff[c]);
      load_lds16(Btl + boff[c] + k0, sBl + ldsoff[c]);
    }
    asm volatile("s_waitcnt vmcnt(0)" ::: "memory");
    __syncthreads();

    bf16x8 ah[4], al[4], bh[4], bl[4];
#pragma unroll
    for (int m = 0; m < 4; m++) {
      const int r = wr * 64 + m * 16 + fr;
      const int off = r * 32 + ((fkg ^ ((r >> 1) & 3)) << 3);
      ah[m] = *(const bf16x8*)(sAh + off);
      al[m] = *(const bf16x8*)(sAl + off);
    }
#pragma unroll
    for (int n = 0; n < 4; n++) {
      const int r = wc * 64 + n * 16 + fr;
      const int off = r * 32 + ((fkg ^ ((r >> 1) & 3)) << 3);
      bh[n] = *(const bf16x8*)(sBh + off);
      bl[n] = *(const bf16x8*)(sBl + off);
    }
#pragma unroll
    for (int m = 0; m < 4; m++)
#pragma unroll
      for (int n = 0; n < 4; n++) {
        acc[m][n] = __builtin_amdgcn_mfma_f32_16x16x32_bf16(ah[m], bh[n], acc[m][n], 0, 0, 0);
        acc[m][n] = __builtin_amdgcn_mfma_f32_16x16x32_bf16(ah[m], bl[n], acc[m][n], 0, 0, 0);
        acc[m][n] = __builtin_amdgcn_mfma_f32_16x16x32_bf16(al[m], bh[n], acc[m][n], 0, 0, 0);
      }
    __syncthreads();
  }

  // epilogue: C/D layout col=lane&15, row=(lane>>4)*4+j
#pragma unroll
  for (int m = 0; m < 4; m++) {
    const int row = bm + wr * 64 + m * 16 + fkg * 4;
#pragma unroll
    for (int n = 0; n < 4; n++) {
      const int col = bn + wc * 64 + n * 16 + fr;
      const float bsv = bias[col];
#pragma unroll
      for (int j = 0; j < 4; j++)
        C[(size_t)(row + j) * Nn + col] = acc[m][n][j] + bsv;
    }
  }
}

// ---------------------------------------------------------------------------
// Vsum[b, d] = sum_n v[b, n, d]   (v inside qkv, row stride LDQKV)
// ---------------------------------------------------------------------------
__global__ __launch_bounds__(256) void vsum_kernel(const float* __restrict__ v,
                                                   float* __restrict__ vsum) {
  const int idx = blockIdx.x * 256 + threadIdx.x;  // b*D + d
  const int b = idx >> 10;
  const int d = idx & (D - 1);
  const float* p = v + (size_t)b * N * LDQKV + d;
  float s = 0.f;
  for (int n = 0; n < N; n++) s += p[(size_t)n * LDQKV];
  vsum[idx] = s;
}

// ---------------------------------------------------------------------------
// pass1: gather-dot over 32 keys, closed-form full-row softmax, out via Vsum
// ---------------------------------------------------------------------------
__global__ __launch_bounds__(64) void attn_pass1(
    const float* __restrict__ qkv, const float* __restrict__ vsum,
    const int* __restrict__ graph, float* __restrict__ pbuf,
    float* __restrict__ basebuf, float* __restrict__ outbuf) {
  const int bid = blockIdx.x;  // (b*H + h)*N + n
  const int n = bid & (N - 1);
  const int h = (bid >> 10) & (H - 1);
  const int b = bid >> 14;
  const int lane = threadIdx.x;

  __shared__ float q_sh[DEPTH];
  __shared__ int g_sh[W];
  __shared__ float p_sh[W];

  const float* qrow = qkv + (size_t)(b * N + n) * LDQKV + h * DEPTH;
  q_sh[lane] = qrow[lane];
  if (lane < W) g_sh[lane] = graph[n * W + lane];
  __syncthreads();

  const int w = lane >> 1;
  const int half = lane & 1;
  const float* krow =
      qkv + 1024 + (size_t)(b * N + g_sh[w]) * LDQKV + h * DEPTH + half * 32;
  float acc = 0.f;
#pragma unroll
  for (int j4 = 0; j4 < 8; j4++) {
    float4 kv = *(const float4*)(krow + j4 * 4);
    const float* qh = &q_sh[half * 32 + j4 * 4];
    acc += kv.x * qh[0] + kv.y * qh[1] + kv.z * qh[2] + kv.w * qh[3];
  }
  acc += __shfl_xor(acc, 1);
  const float dot = acc * 0.125f;

  float m = dot;
#pragma unroll
  for (int off = 2; off < 64; off <<= 1) m = fmaxf(m, __shfl_xor(m, off));
  m = fmaxf(m, 0.f);

  const float e = expf(dot - m);
  float s = e;
#pragma unroll
  for (int off = 1; off < 64; off <<= 1) s += __shfl_xor(s, off);
  s *= 0.5f;

  const float em = expf(-m);
  const float Z = (float)(N - W) * em + s;
  const float inv = 1.f / Z;
  const float base = em * inv;
  const float pw = e * inv;

  if (half == 0) p_sh[w] = pw;
  __syncthreads();

  if (half == 0) pbuf[(size_t)bid * W + w] = pw;
  if (lane == 0) basebuf[bid] = base;

  const float* vbase = qkv + 2048;
  float ov = base * vsum[b * D + h * DEPTH + lane];
#pragma unroll 4
  for (int ww = 0; ww < W; ww++) {
    ov += (p_sh[ww] - base) *
          vbase[(size_t)(b * N + g_sh[ww]) * LDQKV + h * DEPTH + lane];
  }
  outbuf[(size_t)(b * N + n) * D + h * DEPTH + lane] = ov;
}

// ---------------------------------------------------------------------------
// attn row fill: base everywhere, p_w at graph positions
// ---------------------------------------------------------------------------
__global__ __launch_bounds__(256) void attn_fill(
    const float* __restrict__ pbuf, const float* __restrict__ basebuf,
    const int* __restrict__ graph, float* __restrict__ attn) {
  const int bid = blockIdx.x;
  const int n = bid & (N - 1);
  __shared__ float row[N];

  const float base = basebuf[bid];
  float4 b4 = {base, base, base, base};
  float4* row4 = (float4*)row;
  row4[threadIdx.x] = b4;
  __syncthreads();
  if (threadIdx.x < W) {
    const int g = graph[n * W + threadIdx.x];
    row[g] = pbuf[(size_t)bid * W + threadIdx.x];
  }
  __syncthreads();
  float4* dst = (float4*)(attn + (size_t)bid * N);
  dst[threadIdx.x] = row4[threadIdx.x];
}

// ---------------------------------------------------------------------------
extern "C" void kernel_launch(void* const* d_in, const int* in_sizes, int n_in,
                              void* d_out, int out_size, void* d_ws, size_t ws_size,
                              hipStream_t stream) {
  const float* hidden = (const float*)d_in[0];
  const float* wq = (const float*)d_in[1];
  const float* bq = (const float*)d_in[2];
  const float* wk = (const float*)d_in[3];
  const float* bk = (const float*)d_in[4];
  const float* wv = (const float*)d_in[5];
  const float* bv = (const float*)d_in[6];
  const float* wo = (const float*)d_in[7];
  const float* bo = (const float*)d_in[8];
  const int* graph = (const int*)d_in[9];

  float* out0 = (float*)d_out;                 // (B,N,D)
  float* attnp = out0 + (size_t)B * N * D;     // (B,H,N,N) — also scratch arena

  // scratch carved from attn region (fully overwritten by attn_fill at end)
  const size_t M4 = (size_t)4 * 1024 * 1024;   // 4M
  float* qkv = attnp;                          // [4096][3072] f32 (12M floats)
  float* ob = attnp + 3 * M4;                  // [4096][1024] f32 (4M floats)
  unsigned short* ush = (unsigned short*)(attnp + 4 * M4);
  unsigned short* Ahid = ush;                  // 4M ush
  unsigned short* Alid = Ahid + M4;            // 4M
  unsigned short* BTh = Alid + M4;             // 3M  [3072][1024]
  unsigned short* BTl = BTh + 3 * M4 / 4;      // 3M
  unsigned short* Oh = BTl + 3 * M4 / 4;       // 4M
  unsigned short* Ol = Oh + M4;                // 4M
  unsigned short* WoTh = Ol + M4;              // 1M  [1024][1024]
  unsigned short* WoTl = WoTh + M4 / 4;        // 1M
  float* biasq = (float*)(WoTl + M4 / 4);      // 3072 f32

  // small workspace (known to fit from round 0)
  float* pbuf = (float*)d_ws;                  // B*H*N*W
  float* basebuf = pbuf + (size_t)B * H * N * W;
  float* vsumb = basebuf + (size_t)B * H * N;

  cvt_split<<<2048, 256, 0, stream>>>(hidden, Ahid, Alid);
  txp_cvt<<<256, 256, 0, stream>>>(wq, BTh, BTl, 0);
  txp_cvt<<<256, 256, 0, stream>>>(wk, BTh, BTl, 1024);
  txp_cvt<<<256, 256, 0, stream>>>(wv, BTh, BTl, 2048);
  txp_cvt<<<256, 256, 0, stream>>>(wo, WoTh, WoTl, 0);
  bias_concat<<<12, 256, 0, stream>>>(bq, bk, bv, biasq);

  gemm_split<<<dim3(24, 32), 256, 0, stream>>>(Ahid, Alid, BTh, BTl, biasq,
                                               qkv, 1024, 3072);

  vsum_kernel<<<16, 256, 0, stream>>>(qkv + 2048, vsumb);
  attn_pass1<<<B * H * N, 64, 0, stream>>>(qkv, vsumb, graph, pbuf, basebuf, ob);

  cvt_split<<<2048, 256, 0, stream>>>(ob, Oh, Ol);
  gemm_split<<<dim3(8, 32), 256, 0, stream>>>(Oh, Ol, WoTh, WoTl, bo,
                                              out0, 1024, 1024);

  attn_fill<<<B * H * N, 256, 0, stream>>>(pbuf, basebuf, graph, attnp);
}